// Round 1
// baseline (465.690 us; speedup 1.0000x reference)
//
#include <hip/hip_runtime.h>
#include <cstdint>

// FracDownSample: x[16,256,128,128] fp32, w_key[64,256], w_sim[4,64]
// out[16,256,64,64] fp32.  SI=4, SO=2, no padding (128 % 4 == 0).
// One 256-thread block per 4x4 window (16 windows/row * 32 rows * 16 n = 16384 blocks).

#define CIN 256

typedef __attribute__((ext_vector_type(8))) short short8;
typedef __attribute__((ext_vector_type(4))) float floatx4;

__device__ __forceinline__ short f2bf(float f) {
    union { float f; uint32_t u; } v; v.f = f;
    uint32_t u = v.u + 0x7fffu + ((v.u >> 16) & 1u);  // RNE
    return (short)(u >> 16);
}

// Convert w_key (64x256 fp32) -> bf16 in workspace. Runs every launch
// (d_ws is re-poisoned before every timed call).
__global__ void cvt_wkey_kernel(const float* __restrict__ wk,
                                short* __restrict__ wkb) {
    int i = blockIdx.x * 256 + threadIdx.x;   // grid = 64 blocks -> exactly 16384
    wkb[i] = f2bf(wk[i]);
}

__global__ __launch_bounds__(256) void fds_kernel(
    const float* __restrict__ x, const short* __restrict__ wkb,
    const float* __restrict__ wsim, float* __restrict__ out)
{
    // xs rows padded to 260 floats: row stride 1040 B is 16B-aligned (ds_read_b128 ok)
    // and per-dword-phase banks land 2 lanes/bank (free) for the A-fragment reads.
    __shared__ float xs[16][260];     // [pixel p][channel c]
    __shared__ float keyS[16][68];    // relu(key) [pixel][key-channel]
    __shared__ float kqL[64];         // logits [p][s], s-major inner
    __shared__ float wgtS[64];        // softmax weights [p][s]

    const int b   = blockIdx.x;
    // XCD swizzle: assume XCD = b % 8 (perf heuristic only). Gives each XCD a
    // contiguous range of window ids so ww-adjacent windows (which share 64B
    // cache lines on both x reads and out writes) live in one L2.
    const int wid = (b & 7) * 2048 + (b >> 3);
    const int n   = wid >> 10;
    const int hh  = (wid >> 5) & 31;
    const int ww  = wid & 31;

    const int t = threadIdx.x;

    // ---- stage x window (256 c x 4 rows x 4 cols) into LDS ----
    {
        const int c = t;
        const float* xb = x + (((size_t)(n * CIN + c) * 128 + hh * 4) * 128 + ww * 4);
        #pragma unroll
        for (int r = 0; r < 4; ++r) {
            float4 v = *(const float4*)(xb + (size_t)r * 128);
            xs[r * 4 + 0][c] = v.x;
            xs[r * 4 + 1][c] = v.y;
            xs[r * 4 + 2][c] = v.z;
            xs[r * 4 + 3][c] = v.w;
        }
    }
    __syncthreads();

    // ---- key[p][k] = relu( sum_c x[p][c] * w_key[k][c] ) via bf16 MFMA ----
    // Wave wv handles key channels [16*wv, 16*wv+16). A-frag: lane holds
    // A[m = l&15][c = ks*32 + (l>>4)*8 + j]; B-frag: lane holds
    // w_key[n = 16wv + (l&15)][same contiguous c] (B = W^T).
    {
        const int l    = t & 63;
        const int wv   = t >> 6;
        const int mrow = l & 15;
        const int kq8  = (l >> 4) * 8;
        floatx4 acc = {0.f, 0.f, 0.f, 0.f};
        #pragma unroll
        for (int ks = 0; ks < 8; ++ks) {
            const float* ap = &xs[mrow][ks * 32 + kq8];
            short8 af;
            #pragma unroll
            for (int j = 0; j < 8; ++j) af[j] = f2bf(ap[j]);
            short8 bfr = *(const short8*)(wkb + ((wv * 16 + mrow) * 256 + ks * 32 + kq8));
            acc = __builtin_amdgcn_mfma_f32_16x16x32_bf16(af, bfr, acc, 0, 0, 0);
        }
        // D layout: col = lane&15 (key channel), row = (lane>>4)*4 + reg (pixel)
        #pragma unroll
        for (int r = 0; r < 4; ++r) {
            const int p = (l >> 4) * 4 + r;
            keyS[p][wv * 16 + mrow] = fmaxf(acc[r], 0.f);
        }
    }
    __syncthreads();

    // ---- kq logits: kq[p][s] = (1/si) * sum_k keyS[p][k] * w_sim[s][k] ----
    if (t < 64) {
        const int p = t >> 2, s = t & 3;
        float acc = 0.f;
        #pragma unroll 8
        for (int k = 0; k < 64; ++k) acc += keyS[p][k] * wsim[s * 64 + k];
        kqL[t] = acc * 0.25f;   // / si
    }
    __syncthreads();

    // ---- softmax over the 16 pixels (per s) ----
    if (t < 64) {
        const int s = t & 3;
        float m = -1e30f;
        #pragma unroll
        for (int p2 = 0; p2 < 16; ++p2) m = fmaxf(m, kqL[p2 * 4 + s]);
        float sum = 0.f;
        #pragma unroll
        for (int p2 = 0; p2 < 16; ++p2) sum += __expf(kqL[p2 * 4 + s] - m);
        wgtS[t] = __expf(kqL[t] - m) / sum;
    }
    __syncthreads();

    // ---- aggregation: out[c][q] = sum_p xs[p][c] * wgt[p][q]; fp32 ----
    {
        const int c = t;
        float a0 = 0.f, a1 = 0.f, a2 = 0.f, a3 = 0.f;
        #pragma unroll
        for (int p = 0; p < 16; ++p) {
            const float xv = xs[p][c];
            a0 += xv * wgtS[p * 4 + 0];
            a1 += xv * wgtS[p * 4 + 1];
            a2 += xv * wgtS[p * 4 + 2];
            a3 += xv * wgtS[p * 4 + 3];
        }
        // q = qr*2+qc -> out[n][c][2hh+qr][2ww+qc]
        float* ob = out + (((size_t)(n * CIN + c) * 64 + hh * 2) * 64 + ww * 2);
        *(float2*)(ob)      = make_float2(a0, a1);
        *(float2*)(ob + 64) = make_float2(a2, a3);
    }
}

extern "C" void kernel_launch(void* const* d_in, const int* in_sizes, int n_in,
                              void* d_out, int out_size, void* d_ws, size_t ws_size,
                              hipStream_t stream) {
    const float* x    = (const float*)d_in[0];
    const float* wkey = (const float*)d_in[1];
    const float* wsim = (const float*)d_in[2];
    float* out = (float*)d_out;
    short* wkb = (short*)d_ws;   // 64*256 bf16 = 32 KB scratch

    cvt_wkey_kernel<<<64, 256, 0, stream>>>(wkey, wkb);
    fds_kernel<<<16384, 256, 0, stream>>>(x, wkb, wsim, out);
}

// Round 2
// 449.140 us; speedup vs baseline: 1.0368x; 1.0368x over previous
//
#include <hip/hip_runtime.h>
#include <cstdint>

// FracDownSample: x[16,256,128,128] fp32, w_key[64,256], w_sim[4,64]
// out[16,256,64,64] fp32.  SI=4, SO=2, no padding (128 % 4 == 0).
// One 256-thread block per 4x4 window; thread t == channel c.
// R2: bf16 LDS staging (f2bf hoisted out of MFMA loop), fp32 x kept in
// registers for aggregation, kq parallelized over 256 threads, shfl softmax,
// launch_bounds(256,8) -> 8 blocks/CU (LDS ~14 KB).

#define CIN 256

typedef __attribute__((ext_vector_type(8))) short short8;
typedef __attribute__((ext_vector_type(4))) float floatx4;

__device__ __forceinline__ short f2bf_rn(float f) {
    union { float f; uint32_t u; } v; v.f = f;
    uint32_t u = v.u + 0x7fffu + ((v.u >> 16) & 1u);  // RNE
    return (short)(u >> 16);
}
__device__ __forceinline__ short f2bf_rh(float f) {   // round-half-up: 2 ops
    union { float f; uint32_t u; } v; v.f = f;
    return (short)((v.u + 0x8000u) >> 16);
}

// Convert w_key (64x256 fp32) -> bf16 in workspace. Runs every launch
// (d_ws is re-poisoned before every timed call).
__global__ void cvt_wkey_kernel(const float* __restrict__ wk,
                                short* __restrict__ wkb) {
    int i = blockIdx.x * 256 + threadIdx.x;   // 64 blocks -> exactly 16384
    wkb[i] = f2bf_rn(wk[i]);
}

__global__ __launch_bounds__(256, 8) void fds_kernel(
    const float* __restrict__ x, const short* __restrict__ wkb,
    const float* __restrict__ wsim, float* __restrict__ out)
{
    // xs: bf16, rows padded to 264 shorts (528 B, 16B-aligned for b128).
    // Measured r1: this padded-stride pattern gives ~0 bank conflicts.
    __shared__ short xs[16][264];     // [pixel p][channel c] bf16   8.4 KB
    __shared__ float keyS[16][68];    // relu(key) [pixel][k]        4.3 KB
    __shared__ float partS[256];      // kq 4-way K-split partials   1.0 KB
    __shared__ float wgtS[64];        // softmax weights [p*4+s]

    const int b   = blockIdx.x;
    // XCD swizzle (b%8 == XCD heuristic): ww-adjacent windows share 64B x
    // lines and out lines; keep them on one XCD's L2.
    const int wid = (b & 7) * 2048 + (b >> 3);
    const int n   = wid >> 10;
    const int hh  = (wid >> 5) & 31;
    const int ww  = wid & 31;
    const int t   = threadIdx.x;

    // ---- stage: fp32 window into registers, bf16 copy into LDS ----
    float v[16];
    {
        const float* xb = x + (((size_t)(n * CIN + t) * 128 + hh * 4) * 128 + ww * 4);
        float4 r0 = *(const float4*)(xb);
        float4 r1 = *(const float4*)(xb + 128);
        float4 r2 = *(const float4*)(xb + 256);
        float4 r3 = *(const float4*)(xb + 384);
        v[0]=r0.x;  v[1]=r0.y;  v[2]=r0.z;  v[3]=r0.w;
        v[4]=r1.x;  v[5]=r1.y;  v[6]=r1.z;  v[7]=r1.w;
        v[8]=r2.x;  v[9]=r2.y;  v[10]=r2.z; v[11]=r2.w;
        v[12]=r3.x; v[13]=r3.y; v[14]=r3.z; v[15]=r3.w;
        #pragma unroll
        for (int p = 0; p < 16; ++p) xs[p][t] = f2bf_rh(v[p]);
    }
    __syncthreads();

    // ---- key[p][k] = relu( sum_c x[p][c] * w_key[k][c] ), bf16 MFMA ----
    // Wave wv -> key channels [16wv, 16wv+16). A-frag: lane holds
    // A[m=l&15][c = ks*32 + (l>>4)*8 + j] straight from bf16 LDS (b128).
    {
        const int l    = t & 63;
        const int wv   = t >> 6;
        const int mrow = l & 15;
        const int kq8  = (l >> 4) * 8;
        floatx4 acc = {0.f, 0.f, 0.f, 0.f};
        #pragma unroll
        for (int ks = 0; ks < 8; ++ks) {
            short8 af  = *(const short8*)(&xs[mrow][ks * 32 + kq8]);
            short8 bfr = *(const short8*)(wkb + ((wv * 16 + mrow) * 256 + ks * 32 + kq8));
            acc = __builtin_amdgcn_mfma_f32_16x16x32_bf16(af, bfr, acc, 0, 0, 0);
        }
        // D layout: col = lane&15 (key ch), row = (lane>>4)*4 + reg (pixel)
        #pragma unroll
        for (int r = 0; r < 4; ++r)
            keyS[(l >> 4) * 4 + r][wv * 16 + mrow] = fmaxf(acc[r], 0.f);
    }
    __syncthreads();

    // ---- kq partials over all 256 threads: t -> (p, s, k-quarter) ----
    {
        const int p  = t >> 4;
        const int s  = (t >> 2) & 3;
        const int kk = t & 3;
        const float4* kp = (const float4*)&keyS[p][kk * 16];
        const float4* wp = (const float4*)(wsim + s * 64 + kk * 16);
        float acc = 0.f;
        #pragma unroll
        for (int j = 0; j < 4; ++j) {
            float4 kj = kp[j];
            float4 wj = wp[j];
            acc += kj.x * wj.x + kj.y * wj.y + kj.z * wj.z + kj.w * wj.w;
        }
        partS[t] = acc;
    }
    __syncthreads();

    // ---- reduce + softmax over 16 pixels, in-wave (wave 0 only) ----
    if (t < 64) {
        const int p = t >> 2, s = t & 3;   // t == p*4 + s
        float4 pr = *(const float4*)&partS[p * 16 + s * 4];
        float logit = 0.25f * (pr.x + pr.y + pr.z + pr.w);   // / si
        float m = logit;
        #pragma unroll
        for (int msk = 4; msk < 64; msk <<= 1)
            m = fmaxf(m, __shfl_xor(m, msk, 64));
        float e = __expf(logit - m);
        float ssum = e;
        #pragma unroll
        for (int msk = 4; msk < 64; msk <<= 1)
            ssum += __shfl_xor(ssum, msk, 64);
        wgtS[t] = e / ssum;
    }
    __syncthreads();

    // ---- aggregation from registers: out[c][q] = sum_p v[p] * wgt[p][q] ----
    {
        float a0 = 0.f, a1 = 0.f, a2 = 0.f, a3 = 0.f;
        #pragma unroll
        for (int p = 0; p < 16; ++p) {
            float4 wq = *(const float4*)&wgtS[p * 4];   // broadcast b128
            a0 += v[p] * wq.x;
            a1 += v[p] * wq.y;
            a2 += v[p] * wq.z;
            a3 += v[p] * wq.w;
        }
        float* ob = out + (((size_t)(n * CIN + t) * 64 + hh * 2) * 64 + ww * 2);
        *(float2*)(ob)      = make_float2(a0, a1);   // q=(0,0),(0,1)
        *(float2*)(ob + 64) = make_float2(a2, a3);   // q=(1,0),(1,1)
    }
}

extern "C" void kernel_launch(void* const* d_in, const int* in_sizes, int n_in,
                              void* d_out, int out_size, void* d_ws, size_t ws_size,
                              hipStream_t stream) {
    const float* x    = (const float*)d_in[0];
    const float* wkey = (const float*)d_in[1];
    const float* wsim = (const float*)d_in[2];
    float* out = (float*)d_out;
    short* wkb = (short*)d_ws;   // 64*256 bf16 = 32 KB scratch

    cvt_wkey_kernel<<<64, 256, 0, stream>>>(wkey, wkb);
    fds_kernel<<<16384, 256, 0, stream>>>(x, wkb, wsim, out);
}

// Round 3
// 389.276 us; speedup vs baseline: 1.1963x; 1.1538x over previous
//
#include <hip/hip_runtime.h>
#include <cstdint>

// FracDownSample: x[16,256,128,128] fp32, w_key[64,256], w_sim[4,64]
// out[16,256,64,64] fp32.  SI=4, SO=2.
// R3: coalesced restructure. Block = (n, hh, wq) covering 4 adjacent 4x4
// windows (16 cols). Global loads: lanes contiguous along W -> 16 fully-used
// 64B lines per instr (vs 64 quarter-used lines in r2's thread=channel map).
// x transposed through LDS into bf16 [px][c] (serves MFMA-A b128 and
// aggregation b128). 4096 blocks, 256 thr, ~53 KB LDS -> 3 blocks/CU.

#define CIN  256
#define CPAD 264   // bf16 per px row (stride 528 B = 33*16, b128-aligned)
#define KPAD 68    // fp32 per px row in keyS (272 B, 16B-aligned)

typedef __attribute__((ext_vector_type(4))) short short4v;
typedef __attribute__((ext_vector_type(8))) short short8;
typedef __attribute__((ext_vector_type(4))) float floatx4;

__device__ __forceinline__ short f2bf_rn(float f) {
    union { float f; uint32_t u; } v; v.f = f;
    uint32_t u = v.u + 0x7fffu + ((v.u >> 16) & 1u);  // RNE
    return (short)(u >> 16);
}
__device__ __forceinline__ short f2bf_rh(float f) {   // round-half-up, 2 ops
    union { float f; uint32_t u; } v; v.f = f;
    return (short)((v.u + 0x8000u) >> 16);
}
__device__ __forceinline__ float bf2f(short s) {
    union { uint32_t u; float f; } v; v.u = ((uint32_t)(uint16_t)s) << 16;
    return v.f;
}

// w_key fp32 -> bf16 in d_ws (re-done every launch; ws is re-poisoned).
__global__ void cvt_wkey_kernel(const float* __restrict__ wk,
                                short* __restrict__ wkb) {
    int i = blockIdx.x * 256 + threadIdx.x;   // 64 blocks = exactly 16384
    wkb[i] = f2bf_rn(wk[i]);
}

__global__ __launch_bounds__(256, 3) void fds_kernel(
    const float* __restrict__ x, const short* __restrict__ wkb,
    const float* __restrict__ wsim, float* __restrict__ out)
{
    __shared__ alignas(16) short xs[64][CPAD];    // bf16 x, [px][c]  33.0 KB
    __shared__ alignas(16) float keyS[64][KPAD];  // relu keys fp32   17.0 KB
    __shared__ float logitS[64][4];               // kq logits         1 KB
    __shared__ float wgtS[256];                   // [win][s][p]       1 KB
    __shared__ float wsimS[256];                  // staged w_sim      1 KB

    const int b   = blockIdx.x;
    // XCD swizzle (XCD = b%8 heuristic): consecutive wid (adjacent wq, which
    // share output cache lines) stay on one XCD's L2.
    const int wid = (b & 7) * 512 + (b >> 3);
    const int n   = wid >> 8;
    const int hh  = (wid >> 3) & 31;
    const int wq  = wid & 7;
    const int t   = threadIdx.x;

    if (t < 64) *(float4*)&wsimS[t * 4] = *(const float4*)(wsim + t * 4);

    // ---- phase 1: coalesced load + bf16 transpose into LDS [px][c] ----
    // idx = i*256+t: colg = idx&3 (4-col group), r = (idx>>2)&3 (window row),
    // cg = idx>>4 (4-channel group). Each thread loads the same 16B of 4
    // consecutive channels -> packs bf16 along c -> b64 LDS writes.
    #pragma unroll
    for (int i = 0; i < 4; ++i) {
        const int idx  = i * 256 + t;
        const int colg = idx & 3, r = (idx >> 2) & 3, cg = idx >> 4;
        const float* xb = x + ((size_t)(n * CIN + cg * 4) << 14)
                            + (hh * 4 + r) * 128 + wq * 16 + colg * 4;
        float4 v0 = *(const float4*)(xb);
        float4 v1 = *(const float4*)(xb + 16384);
        float4 v2 = *(const float4*)(xb + 32768);
        float4 v3 = *(const float4*)(xb + 49152);
        const int pxb = colg * 16 + r * 4;   // win = colg, p = r*4 + j
        short4v w0 = { f2bf_rh(v0.x), f2bf_rh(v1.x), f2bf_rh(v2.x), f2bf_rh(v3.x) };
        short4v w1 = { f2bf_rh(v0.y), f2bf_rh(v1.y), f2bf_rh(v2.y), f2bf_rh(v3.y) };
        short4v w2 = { f2bf_rh(v0.z), f2bf_rh(v1.z), f2bf_rh(v2.z), f2bf_rh(v3.z) };
        short4v w3 = { f2bf_rh(v0.w), f2bf_rh(v1.w), f2bf_rh(v2.w), f2bf_rh(v3.w) };
        *(short4v*)&xs[pxb + 0][cg * 4] = w0;
        *(short4v*)&xs[pxb + 1][cg * 4] = w1;
        *(short4v*)&xs[pxb + 2][cg * 4] = w2;
        *(short4v*)&xs[pxb + 3][cg * 4] = w3;
    }
    __syncthreads();

    // ---- phase 2: keys via MFMA. Wave wv owns key-tile [16wv,16wv+16),
    // all 4 px-tiles. B preloaded (8 b128 global, L1/L2-hot), A from LDS. ----
    {
        const int l = t & 63, wv = t >> 6;
        const int kr = l & 15, kq8 = (l >> 4) * 8;
        short8 bfr[8];
        #pragma unroll
        for (int ks = 0; ks < 8; ++ks)
            bfr[ks] = *(const short8*)(wkb + (wv * 16 + kr) * 256 + ks * 32 + kq8);
        #pragma unroll
        for (int mt = 0; mt < 4; ++mt) {
            floatx4 acc = {0.f, 0.f, 0.f, 0.f};
            #pragma unroll
            for (int ks = 0; ks < 8; ++ks) {
                short8 af = *(const short8*)(&xs[mt * 16 + kr][ks * 32 + kq8]);
                acc = __builtin_amdgcn_mfma_f32_16x16x32_bf16(af, bfr[ks], acc, 0, 0, 0);
            }
            // D: col = l&15 (key), row = (l>>4)*4 + reg (pixel)
            #pragma unroll
            for (int rg = 0; rg < 4; ++rg)
                keyS[mt * 16 + (l >> 4) * 4 + rg][wv * 16 + kr] = fmaxf(acc[rg], 0.f);
        }
    }
    __syncthreads();

    // ---- phase 3: kq logits; t -> (px = t>>2, s = t&3), dot over 64 keys ----
    {
        const int px = t >> 2, s = t & 3;
        float acc = 0.f;
        #pragma unroll
        for (int kk = 0; kk < 16; ++kk) {
            float4 kv = *(const float4*)&keyS[px][kk * 4];
            float4 wv4 = *(const float4*)&wsimS[s * 64 + kk * 4];
            acc += kv.x * wv4.x + kv.y * wv4.y + kv.z * wv4.z + kv.w * wv4.w;
        }
        logitS[px][s] = acc * 0.25f;   // / si
    }
    __syncthreads();

    // ---- phase 4: softmax over p within (win, s); wave = win, groups of 16 ----
    {
        const int p = t & 15, win = t >> 6;
        float lg = logitS[win * 16 + p][(t >> 4) & 3];
        float m = lg;
        #pragma unroll
        for (int msk = 1; msk < 16; msk <<= 1)
            m = fmaxf(m, __shfl_xor(m, msk, 64));
        float e = __expf(lg - m);
        float ssum = e;
        #pragma unroll
        for (int msk = 1; msk < 16; msk <<= 1)
            ssum += __shfl_xor(ssum, msk, 64);
        wgtS[t] = e / ssum;   // layout [win][s][p] == thread order
    }
    __syncthreads();

    // ---- phase 5: aggregation. t -> (oc = t&7, or = (t>>3)&1, cgrp = t>>4).
    // win = oc>>1, q = or*2 + (oc&1) fixed per thread; 16 channels each. ----
    {
        const int oc = t & 7, orr = (t >> 3) & 1, cgrp = t >> 4;
        const int win = oc >> 1, q = orr * 2 + (oc & 1);
        float wg[16];
        #pragma unroll
        for (int pk = 0; pk < 4; ++pk)
            *(float4*)&wg[pk * 4] = *(const float4*)&wgtS[win * 64 + q * 16 + pk * 4];
        float acc[16];
        #pragma unroll
        for (int i = 0; i < 16; ++i) acc[i] = 0.f;
        #pragma unroll
        for (int p = 0; p < 16; ++p) {
            const short* row = &xs[win * 16 + p][cgrp * 16];
            short8 xa = *(const short8*)(row);
            short8 xb2 = *(const short8*)(row + 8);
            const float w = wg[p];
            #pragma unroll
            for (int j = 0; j < 8; ++j) {
                acc[j]     += bf2f(xa[j])  * w;
                acc[8 + j] += bf2f(xb2[j]) * w;
            }
        }
        float* ob = out + ((size_t)(n * CIN + cgrp * 16) << 12)
                        + (hh * 2 + orr) * 64 + wq * 8 + oc;
        #pragma unroll
        for (int i = 0; i < 16; ++i)
            ob[(size_t)i << 12] = acc[i];
    }
}

extern "C" void kernel_launch(void* const* d_in, const int* in_sizes, int n_in,
                              void* d_out, int out_size, void* d_ws, size_t ws_size,
                              hipStream_t stream) {
    const float* x    = (const float*)d_in[0];
    const float* wkey = (const float*)d_in[1];
    const float* wsim = (const float*)d_in[2];
    float* out = (float*)d_out;
    short* wkb = (short*)d_ws;   // 64*256 bf16 = 32 KB scratch

    cvt_wkey_kernel<<<64, 256, 0, stream>>>(wkey, wkb);
    fds_kernel<<<4096, 256, 0, stream>>>(x, wkb, wsim, out);
}